// Round 13
// baseline (432.319 us; speedup 1.0000x reference)
//
#include <hip/hip_runtime.h>
#include <stdint.h>

#define B 8192
#define T 512
#define K 24

__device__ __forceinline__ float max3f(float a, float b, float c) {
    return fmaxf(fmaxf(a, b), c);   // fuses to v_max3_f32
}

#define XG(v) __builtin_amdgcn_ds_swizzle((v), 0x101F)                 /* xor4 */
#define D2(v) __builtin_amdgcn_mov_dpp((v), 0x4E, 0xF, 0xF, true)      /* xor2 */
#define D1(v) __builtin_amdgcn_mov_dpp((v), 0xB1, 0xF, 0xF, true)      /* xor1 */

// One Viterbi step for one batch-chain. Butterfly all-gather of the 8-lane
// group's 24 alpha values (3 ds_swizzle xor4 + 6 DPP xor2 + 12 DPP xor1);
// slots land in lane-relative row order (slot 3k+c = row 3*(l^X[k])+c,
// X={0,4,2,6,1,5,3,7}) matching the tcr permutation done once at init.
// Order-free exact max via v_max3 tree; alpha row written to gp[0..2].
__device__ __forceinline__ void vstep(float& n0, float& n1, float& n2,
                                      float e0, float e1, float e2,
                                      const float (&tcr)[3][K], float* gp)
{
    const int i0 = __float_as_int(n0);
    const int i1 = __float_as_int(n1);
    const int i2 = __float_as_int(n2);
    const int b0 = XG(i0), b1 = XG(i1), b2 = XG(i2);
    const int q0 = D2(i0), q1 = D2(i1), q2 = D2(i2);
    const int q3 = D2(b0), q4 = D2(b1), q5 = D2(b2);
    const int d0 = D1(i0), d1 = D1(i1), d2  = D1(i2);
    const int d3 = D1(b0), d4 = D1(b1), d5  = D1(b2);
    const int d6 = D1(q0), d7 = D1(q1), d8  = D1(q2);
    const int d9 = D1(q3), d10 = D1(q4), d11 = D1(q5);

    float s[K];
    s[0]  = n0;                   s[1]  = n1;
    s[2]  = n2;                   s[3]  = __int_as_float(b0);
    s[4]  = __int_as_float(b1);   s[5]  = __int_as_float(b2);
    s[6]  = __int_as_float(q0);   s[7]  = __int_as_float(q1);
    s[8]  = __int_as_float(q2);   s[9]  = __int_as_float(q3);
    s[10] = __int_as_float(q4);   s[11] = __int_as_float(q5);
    s[12] = __int_as_float(d0);   s[13] = __int_as_float(d1);
    s[14] = __int_as_float(d2);   s[15] = __int_as_float(d3);
    s[16] = __int_as_float(d4);   s[17] = __int_as_float(d5);
    s[18] = __int_as_float(d6);   s[19] = __int_as_float(d7);
    s[20] = __int_as_float(d8);   s[21] = __int_as_float(d9);
    s[22] = __int_as_float(d10);  s[23] = __int_as_float(d11);

    float r[3];
#pragma unroll
    for (int j = 0; j < 3; ++j) {
        float u[8];
#pragma unroll
        for (int k = 0; k < 8; ++k)
            u[k] = max3f(s[3*k]   + tcr[j][3*k],
                         s[3*k+1] + tcr[j][3*k+1],
                         s[3*k+2] + tcr[j][3*k+2]);
        float w0 = max3f(u[0], u[1], u[2]);
        float w1 = max3f(u[3], u[4], u[5]);
        float w2 = fmaxf(u[6], u[7]);
        r[j] = max3f(w0, w1, w2);
    }
    n0 = r[0] + e0; n1 = r[1] + e1; n2 = r[2] + e2;
    gp[0] = n0; gp[1] = n1; gp[2] = n2;
}

// ---------------------------------------------------------------------------
// Forward Viterbi, VALUE-ONLY, register-resident alpha, TWO independent
// batch-chains per lane. 64-thread block = one wave = 8-lane groups x 8;
// each group serves batches b1 (chain A) and b1+4096 (chain B). The chains
// interleave per step: chain B's VALU fills chain A's swizzle-wait / dep
// stalls (measured 42% idle at 1 chain). tcr is SHARED between chains.
// 512 blocks; per-wave latency-bound, so fewer waves is free. 4-step-deep
// emission prefetch ring per chain. Alpha_t streams to d_out[b][t][:];
// backtrack recomputes the exact argmax from it.
// ---------------------------------------------------------------------------
__global__ __launch_bounds__(64) __attribute__((amdgpu_waves_per_eu(1, 1)))
void crf_forward(const float* __restrict__ inp,    // [B, T, K]
                 const float* __restrict__ trans,  // [K, K] (prev i -> cur j)
                 float* __restrict__ out)          // [B, T, K] <- alpha
{
    const int lane = threadIdx.x;          // one wave per block
    const int g    = lane >> 3;            // batch group 0..7
    const int l    = lane & 7;             // lane within group
    const int c0   = 3 * l;                // this lane's columns c0..c0+2
    const int bA   = blockIdx.x * 8 + g;   // 512 blocks * 8 = 4096
    const int bB   = bA + 4096;

    // tc permuted to gather order: tcr[j][3k+c] = trans[3*(l^X[k])+c][c0+j]
    const int X[8] = {0, 4, 2, 6, 1, 5, 3, 7};
    float tcr[3][K];
#pragma unroll
    for (int j = 0; j < 3; ++j)
#pragma unroll
        for (int k = 0; k < 8; ++k) {
            const int rl = 3 * (l ^ X[k]);
#pragma unroll
            for (int c = 0; c < 3; ++c)
                tcr[j][3 * k + c] = trans[(rl + c) * K + c0 + j];
        }

    const float* eblA = inp + (size_t)bA * T * K + c0;
    const float* eblB = inp + (size_t)bB * T * K + c0;
    float*       oblA = out + (size_t)bA * T * K + c0;
    float*       oblB = out + (size_t)bB * T * K + c0;

    float nA0, nA1, nA2, nB0, nB1, nB2;    // own alpha rows, both chains
    {   // t = 0: alpha_0 = emissions_0
        nA0 = eblA[0]; nA1 = eblA[1]; nA2 = eblA[2];
        oblA[0] = nA0; oblA[1] = nA1; oblA[2] = nA2;
        nB0 = eblB[0]; nB1 = eblB[1]; nB2 = eblB[2];
        oblB[0] = nB0; oblB[1] = nB1; oblB[2] = nB2;
    }

    // emission rings: e{A..D}{chain} hold e(t)..e(t+3)
    float eAa0 = eblA[1*K], eAa1 = eblA[1*K+1], eAa2 = eblA[1*K+2];
    float eAb0 = eblA[2*K], eAb1 = eblA[2*K+1], eAb2 = eblA[2*K+2];
    float eAc0 = eblA[3*K], eAc1 = eblA[3*K+1], eAc2 = eblA[3*K+2];
    float eAd0 = eblA[4*K], eAd1 = eblA[4*K+1], eAd2 = eblA[4*K+2];
    float eBa0 = eblB[1*K], eBa1 = eblB[1*K+1], eBa2 = eblB[1*K+2];
    float eBb0 = eblB[2*K], eBb1 = eblB[2*K+1], eBb2 = eblB[2*K+2];
    float eBc0 = eblB[3*K], eBc1 = eblB[3*K+1], eBc2 = eblB[3*K+2];
    float eBd0 = eblB[4*K], eBd1 = eblB[4*K+1], eBd2 = eblB[4*K+2];

#pragma unroll 1
    for (int ch = 0; ch < 127; ++ch) {
        const int t = 1 + 4 * ch;              // 1,5,...,505
        // preload e(t+4..t+7) for both chains (t+7 clamped on last iter)
        const float* pா4A = eblA + (size_t)(t + 4) * K;
        const float* p5A = eblA + (size_t)(t + 5) * K;
        const float* p6A = eblA + (size_t)(t + 6) * K;
        int t7 = t + 7; t7 = t7 > 511 ? 511 : t7;
        const float* p7A = eblA + (size_t)t7 * K;
        const float* p4B = eblB + (size_t)(t + 4) * K;
        const float* p5B = eblB + (size_t)(t + 5) * K;
        const float* p6B = eblB + (size_t)(t + 6) * K;
        const float* p7B = eblB + (size_t)t7 * K;
        float mAa0 = pா4A[0], mAa1 = pா4A[1], mAa2 = pா4A[2];
        float mAb0 = p5A[0], mAb1 = p5A[1], mAb2 = p5A[2];
        float mAc0 = p6A[0], mAc1 = p6A[1], mAc2 = p6A[2];
        float mAd0 = p7A[0], mAd1 = p7A[1], mAd2 = p7A[2];
        float mBa0 = p4B[0], mBa1 = p4B[1], mBa2 = p4B[2];
        float mBb0 = p5B[0], mBb1 = p5B[1], mBb2 = p5B[2];
        float mBc0 = p6B[0], mBc1 = p6B[1], mBc2 = p6B[2];
        float mBd0 = p7B[0], mBd1 = p7B[1], mBd2 = p7B[2];

        vstep(nA0, nA1, nA2, eAa0, eAa1, eAa2, tcr, oblA + (size_t)(t    ) * K);
        vstep(nB0, nB1, nB2, eBa0, eBa1, eBa2, tcr, oblB + (size_t)(t    ) * K);
        vstep(nA0, nA1, nA2, eAb0, eAb1, eAb2, tcr, oblA + (size_t)(t + 1) * K);
        vstep(nB0, nB1, nB2, eBb0, eBb1, eBb2, tcr, oblB + (size_t)(t + 1) * K);
        vstep(nA0, nA1, nA2, eAc0, eAc1, eAc2, tcr, oblA + (size_t)(t + 2) * K);
        vstep(nB0, nB1, nB2, eBc0, eBc1, eBc2, tcr, oblB + (size_t)(t + 2) * K);
        vstep(nA0, nA1, nA2, eAd0, eAd1, eAd2, tcr, oblA + (size_t)(t + 3) * K);
        vstep(nB0, nB1, nB2, eBd0, eBd1, eBd2, tcr, oblB + (size_t)(t + 3) * K);

        eAa0 = mAa0; eAa1 = mAa1; eAa2 = mAa2;
        eAb0 = mAb0; eAb1 = mAb1; eAb2 = mAb2;
        eAc0 = mAc0; eAc1 = mAc1; eAc2 = mAc2;
        eAd0 = mAd0; eAd1 = mAd1; eAd2 = mAd2;
        eBa0 = mBa0; eBa1 = mBa1; eBa2 = mBa2;
        eBb0 = mBb0; eBb1 = mBb1; eBb2 = mBb2;
        eBc0 = mBc0; eBc1 = mBc1; eBc2 = mBc2;
        eBd0 = mBd0; eBd1 = mBd1; eBd2 = mBd2;
    }
    // tail: t = 509, 510, 511
    vstep(nA0, nA1, nA2, eAa0, eAa1, eAa2, tcr, oblA + (size_t)509 * K);
    vstep(nB0, nB1, nB2, eBa0, eBa1, eBa2, tcr, oblB + (size_t)509 * K);
    vstep(nA0, nA1, nA2, eAb0, eAb1, eAb2, tcr, oblA + (size_t)510 * K);
    vstep(nB0, nB1, nB2, eBb0, eBb1, eBb2, tcr, oblB + (size_t)510 * K);
    vstep(nA0, nA1, nA2, eAc0, eAc1, eAc2, tcr, oblA + (size_t)511 * K);
    vstep(nB0, nB1, nB2, eBc0, eBc1, eBc2, tcr, oblB + (size_t)511 * K);
}

#undef XG
#undef D2
#undef D1

// ---------------------------------------------------------------------------
// 32-lane-group max reduce, all lanes receive the max. 4 DPP steps (VALU
// latency) + 1 ds_swizzle xor-16. Exact (fmax of finite floats).
// ---------------------------------------------------------------------------
__device__ __forceinline__ float groupmax32(float v) {
    float t;
    t = __int_as_float(__builtin_amdgcn_mov_dpp(__float_as_int(v), 0xB1, 0xF, 0xF, true));   // quad_perm [1,0,3,2]
    v = fmaxf(v, t);
    t = __int_as_float(__builtin_amdgcn_mov_dpp(__float_as_int(v), 0x4E, 0xF, 0xF, true));   // quad_perm [2,3,0,1]
    v = fmaxf(v, t);
    t = __int_as_float(__builtin_amdgcn_mov_dpp(__float_as_int(v), 0x141, 0xF, 0xF, true));  // row_half_mirror
    v = fmaxf(v, t);
    t = __int_as_float(__builtin_amdgcn_mov_dpp(__float_as_int(v), 0x140, 0xF, 0xF, true));  // row_mirror
    v = fmaxf(v, t);
    t = __int_as_float(__builtin_amdgcn_ds_swizzle(__float_as_int(v), 0x401F));              // xor 16
    v = fmaxf(v, t);
    return v;
}

// ---------------------------------------------------------------------------
// Fused backtrack + one-hot (unchanged — measured at the HBM floor).
// 32 lanes per batch, 2 batches/wave, 4096 waves. Per step: prefetched
// alpha_t[i] (8-deep rotation) + trans[i][cur] from stride-25 LDS -> DPP
// value-max -> cur = ctz(ballot(s == M)) (exact first-index) -> one-hot.
// ---------------------------------------------------------------------------
__global__ __launch_bounds__(256) __attribute__((amdgpu_waves_per_eu(4, 4)))
void crf_backtrack(const float* __restrict__ trans,  // [K, K]
                   float* __restrict__ out)          // [B,T,K] alpha->onehot
{
    __shared__ float tl[K * 25];      // tl[i*25 + j] = trans[i][j]

    const int tid = threadIdx.x;
    for (int idx = tid; idx < K * K; idx += 256) {
        int i = idx / K, j = idx - K * i;
        tl[i * 25 + j] = trans[idx];
    }
    __syncthreads();

    const int lane = tid & 63;
    const int half = lane >> 5;            // batch within wave (0/1)
    const int i    = lane & 31;            // tag row (24..31 idle)
    const int wv   = tid >> 6;
    const int b    = blockIdx.x * 8 + wv * 2 + half;
    const int shmt = half * 32;

    const bool act = (i < K);
    const int  io  = act ? i : (K - 1);

    float* ob = out + (size_t)b * T * K;
    const float* rp  = ob + (size_t)511 * K + io;   // prefetch pointer
    float*       wpp = ob + (size_t)511 * K + io;   // write pointer

    float q[8];                            // slot = t & 7
#pragma unroll
    for (int s = 0; s < 8; ++s) { q[7 - s] = *rp; rp -= K; }   // t=511..504

    int cur;
    {   // t = 511: last_tag = first-index argmax of alpha_511
        float s = act ? q[7] : -INFINITY;
        float M = groupmax32(s);
        uint32_t m32 = (uint32_t)(__ballot(s == M) >> shmt);
        cur = (int)__builtin_ctz(m32);
        if (act) *wpp = (i == cur) ? 1.0f : 0.0f;
        wpp -= K;
        q[7] = *rp; rp -= K;               // prefetch t=503 into slot 7
    }

#define STEP_BT(S, TT) do {                                                   \
    float tv_ = tl[io * 25 + cur];                                            \
    float s_  = act ? (q[S] + tv_) : -INFINITY;                               \
    float M_  = groupmax32(s_);                                               \
    uint32_t m32_ = (uint32_t)(__ballot(s_ == M_) >> shmt);                   \
    cur = (int)__builtin_ctz(m32_);                                           \
    if (act) *wpp = (i == cur) ? 1.0f : 0.0f;                                 \
    wpp -= K;                                                                 \
    if ((TT) >= 8) { q[S] = *rp; rp -= K; }                                   \
} while (0)

#pragma unroll 1
    for (int it = 0; it < 63; ++it) {      // t = 510 .. 7
        const int t0 = 510 - 8 * it;
        STEP_BT(6, t0);     STEP_BT(5, t0 - 1);
        STEP_BT(4, t0 - 2); STEP_BT(3, t0 - 3);
        STEP_BT(2, t0 - 4); STEP_BT(1, t0 - 5);
        STEP_BT(0, t0 - 6); STEP_BT(7, t0 - 7);
    }
    // epilogue: t = 6..0 (all slots already resident)
    STEP_BT(6, 6); STEP_BT(5, 5); STEP_BT(4, 4);
    STEP_BT(3, 3); STEP_BT(2, 2); STEP_BT(1, 1); STEP_BT(0, 0);
#undef STEP_BT
}

extern "C" void kernel_launch(void* const* d_in, const int* in_sizes, int n_in,
                              void* d_out, int out_size, void* d_ws, size_t ws_size,
                              hipStream_t stream) {
    const float* inp   = (const float*)d_in[0];   // [8192, 512, 24]
    const float* trans = (const float*)d_in[1];   // [24, 24]
    float*       out   = (float*)d_out;           // [8192, 512, 24]

    crf_forward<<<B / 16, 64, 0, stream>>>(inp, trans, out);
    crf_backtrack<<<B / 8, 256, 0, stream>>>(trans, out);
}